// Round 8
// baseline (130.714 us; speedup 1.0000x reference)
//
#include <hip/hip_runtime.h>
#include <cstdint>
#include <cstddef>

#define DD    2048
#define NE    8
#define NTOK  4096
#define CAP   512
#define TPB   4                       // tokens per k_logits block
#define NBLK  (NTOK / TPB)            // 1024
#define DISP_ELEMS (NTOK * NE * CAP)  // 16,777,216 floats
#define GATES_OFF  DISP_ELEMS
#define IDX_OFF    (DISP_ELEMS + NTOK * 2)
#define SLICE      (TPB * NE * CAP)   // 16384 floats = 64 KB per block

// ---------------------------------------------------------------------------
// k_pre: transpose W[2048][8] -> WT[8][2048] (64 KB, L2-resident afterwards).
// ---------------------------------------------------------------------------
__global__ __launch_bounds__(256) void k_pre(
    const float* __restrict__ W, float* __restrict__ WT)
{
    const int d = blockIdx.x * 256 + threadIdx.x;    // 0..2047
    const float4* W4 = reinterpret_cast<const float4*>(W);
    float4 a = W4[d * 2];        // W[d][0..3]
    float4 b = W4[d * 2 + 1];    // W[d][4..7]
    WT[0 * DD + d] = a.x; WT[1 * DD + d] = a.y;
    WT[2 * DD + d] = a.z; WT[3 * DD + d] = a.w;
    WT[4 * DD + d] = b.x; WT[5 * DD + d] = b.y;
    WT[6 * DD + d] = b.z; WT[7 * DD + d] = b.w;
}

// ---------------------------------------------------------------------------
// k_logits: 1024 blocks x 256. Block = 4 tokens.
//   - zero own 64 KB dispatcher slice (independent stores, issued first)
//   - logits: e = tid>>5 (half-wave per expert), seg = tid&31.
//     Thread's dims: {4*seg + 128*j + c}. WT/x reads are coalesced float4;
//     the two half-waves of a wave read identical x addresses (broadcast).
//     Each half-wave computes the COMPLETE dot for its (e, 4 tokens):
//     5-level shfl_xor reduce, no LDS staging, no cross-wave combine.
//   - top-2 + softmax + choices + histT[pair][block]
// ---------------------------------------------------------------------------
__global__ __launch_bounds__(256, 4) void k_logits(
    const float* __restrict__ x, const float* __restrict__ WT,
    float* __restrict__ out, int2* __restrict__ choices,
    unsigned* __restrict__ histT)
{
    const int tid  = threadIdx.x;
    const int bid  = blockIdx.x;
    const int e    = tid >> 5;        // 0..7 (half-wave per expert)
    const int seg  = tid & 31;        // 0..31
    const int lane = tid & 63;

    __shared__ double redbuf[TPB][NE];
    __shared__ int2   chs[TPB];

    // ---- zero this block's 64 KB dispatcher slice (no dependencies) -----
    {
        float4 z = make_float4(0.f, 0.f, 0.f, 0.f);
        float4* dp = reinterpret_cast<float4*>(out) + (size_t)bid * (SLICE / 4);
        #pragma unroll
        for (int i = 0; i < (SLICE / 4) / 256; ++i)            // 16
            dp[i * 256 + tid] = z;
    }

    // ---- WT slice: 16 coalesced float4 (64 dims of expert e) ------------
    const float4* WT4 = reinterpret_cast<const float4*>(WT);
    float4 wt[16];
    #pragma unroll
    for (int j = 0; j < 16; ++j)
        wt[j] = WT4[e * (DD / 4) + seg + 32 * j];

    // ---- f64 dot, 4 tokens, direct global x reads -----------------------
    const float4* x4 = reinterpret_cast<const float4*>(x);
    double acc[TPB] = {0.0, 0.0, 0.0, 0.0};
    #pragma unroll
    for (int j = 0; j < 16; ++j) {
        #pragma unroll
        for (int t = 0; t < TPB; ++t) {
            float4 v = x4[(size_t)(bid * TPB + t) * (DD / 4) + seg + 32 * j];
            acc[t] += (double)v.x * (double)wt[j].x;
            acc[t] += (double)v.y * (double)wt[j].y;
            acc[t] += (double)v.z * (double)wt[j].z;
            acc[t] += (double)v.w * (double)wt[j].w;
        }
    }

    // ---- reduce across the 32 lanes of this half-wave -------------------
    #pragma unroll
    for (int off = 1; off < 32; off <<= 1) {
        #pragma unroll
        for (int t = 0; t < TPB; ++t)
            acc[t] += __shfl_xor(acc[t], off, 64);
    }
    if ((lane & 31) == 0) {
        #pragma unroll
        for (int t = 0; t < TPB; ++t)
            redbuf[t][e] = acc[t];
    }
    __syncthreads();

    // ---- per-token finalize: threads 0..3 -------------------------------
    if (tid < TPB) {
        const int t = tid;
        const int n = bid * TPB + t;
        float lg[NE];
        #pragma unroll
        for (int q = 0; q < NE; ++q) lg[q] = (float)redbuf[t][q];

        int e0 = 0;
        #pragma unroll
        for (int q = 1; q < NE; ++q) if (lg[q] > lg[e0]) e0 = q;
        int e1 = -1;
        #pragma unroll
        for (int q = 0; q < NE; ++q) {
            if (q == e0) continue;
            if (e1 < 0 || lg[q] > lg[e1]) e1 = q;
        }

        float p1 = __expf(lg[e1] - lg[e0]);    // lg[e0] >= lg[e1]
        float s  = 1.0f + p1;
        out[GATES_OFF + n * 2 + 0] = 1.0f / s;
        out[GATES_OFF + n * 2 + 1] = p1 / s;
        out[IDX_OFF   + n * 2 + 0] = (float)e0;
        out[IDX_OFF   + n * 2 + 1] = (float)e1;
        int2 c; c.x = e0; c.y = e1;
        choices[n] = c;
        chs[t] = c;
    }
    __syncthreads();

    // ---- per-block histogram, transposed layout histT[pair][block] ------
    if (tid < 16) {
        const int k = tid >> 3, ee = tid & 7;
        unsigned c = 0;
        #pragma unroll
        for (int t = 0; t < TPB; ++t) {
            int v = k ? chs[t].y : chs[t].x;
            c += (v == ee);
        }
        histT[tid * NBLK + bid] = c;
    }
}

// ---------------------------------------------------------------------------
// k_scan16: 1 block x 1024 (16 waves). Wave p: exclusive scan of
// histT[p][0..1023] -> histP[block][pair] (block-major for k_patch reads).
// ---------------------------------------------------------------------------
__global__ __launch_bounds__(1024) void k_scan16(
    const unsigned* __restrict__ histT, unsigned* __restrict__ histP)
{
    const int lane = threadIdx.x & 63;
    const int p    = threadIdx.x >> 6;     // 0..15

    unsigned running = 0;
    #pragma unroll
    for (int chunk = 0; chunk < 16; ++chunk) {
        const int b = chunk * 64 + lane;
        unsigned v = histT[p * NBLK + b];
        unsigned incl = v;
        #pragma unroll
        for (int off = 1; off < 64; off <<= 1) {
            unsigned u = __shfl_up(incl, off, 64);
            if (lane >= off) incl += u;
        }
        histP[b * 16 + p] = incl - v + running;
        running += __shfl(incl, 63, 64);
    }
}

// ---------------------------------------------------------------------------
// k_patch: 4 blocks x 256 = 1024 threads; thread ab owns one 4-token block.
// Dispatcher already zeroed by k_logits; just write the <=8 ones.
// ---------------------------------------------------------------------------
__global__ __launch_bounds__(256) void k_patch(
    const int2* __restrict__ choices, const unsigned* __restrict__ histP,
    float* __restrict__ out)
{
    const int ab = blockIdx.x * 256 + threadIdx.x;   // 0..1023

    int2 c[TPB];
    #pragma unroll
    for (int t = 0; t < TPB; ++t) c[t] = choices[ab * TPB + t];

    uint4 b0 = reinterpret_cast<const uint4*>(histP + ab * 16)[0];
    uint4 b1 = reinterpret_cast<const uint4*>(histP + ab * 16)[1];
    uint4 b2 = reinterpret_cast<const uint4*>(histP + ab * 16)[2];
    uint4 b3 = reinterpret_cast<const uint4*>(histP + ab * 16)[3];
    unsigned base[16] = {b0.x, b0.y, b0.z, b0.w, b1.x, b1.y, b1.z, b1.w,
                         b2.x, b2.y, b2.z, b2.w, b3.x, b3.y, b3.z, b3.w};

    #pragma unroll
    for (int t = 0; t < TPB; ++t) {
        const int n = ab * TPB + t;
        const int e0 = c[t].x;
        unsigned r = 0;
        #pragma unroll
        for (int m = 0; m < TPB; ++m) if (m < t) r += (c[m].x == e0);
        const unsigned p0 = base[e0] + r;
        if (p0 < CAP) out[((size_t)n * NE + e0) * CAP + p0] = 1.0f;

        const int e1 = c[t].y;
        r = 0;
        #pragma unroll
        for (int m = 0; m < TPB; ++m) if (m < t) r += (c[m].y == e1);
        const unsigned p1 = base[8 + e1] + r;
        if (p1 < CAP) out[((size_t)n * NE + e1) * CAP + p1] = 1.0f;
    }
}

extern "C" void kernel_launch(void* const* d_in, const int* in_sizes, int n_in,
                              void* d_out, int out_size, void* d_ws, size_t ws_size,
                              hipStream_t stream) {
    const float* x = (const float*)d_in[0];
    const float* W = (const float*)d_in[1];
    float* out     = (float*)d_out;

    char* ws = (char*)d_ws;
    float*    WT      = (float*)ws;                       // 64 KB
    int2*     choices = (int2*)(ws + 65536);              // 32 KB
    unsigned* histT   = (unsigned*)(ws + 65536 + 32768);  // 64 KB
    unsigned* histP   = (unsigned*)(ws + 65536 + 32768 + 65536); // 64 KB

    hipLaunchKernelGGL(k_pre,    dim3(8),    dim3(256),  0, stream, W, WT);
    hipLaunchKernelGGL(k_logits, dim3(NBLK), dim3(256),  0, stream,
                       x, WT, out, choices, histT);
    hipLaunchKernelGGL(k_scan16, dim3(1),    dim3(1024), 0, stream, histT, histP);
    hipLaunchKernelGGL(k_patch,  dim3(4),    dim3(256),  0, stream,
                       choices, histP, out);
}

// Round 11
// 117.880 us; speedup vs baseline: 1.1089x; 1.1089x over previous
//
#include <hip/hip_runtime.h>
#include <cstdint>
#include <cstddef>

#define DD    2048
#define NE    8
#define NTOK  4096
#define CAP   512
#define DISP_ELEMS (NTOK * NE * CAP)  // 16,777,216 floats
#define GATES_OFF  DISP_ELEMS
#define IDX_OFF    (DISP_ELEMS + NTOK * 2)
#define ZBLK  2048                    // zero-role blocks
#define NGRP  1024                    // 4-token groups

// ---------------------------------------------------------------------------
// k_pre: transpose W[2048][8] -> WT[8][2048] (64 KB, L2-resident afterwards).
// ---------------------------------------------------------------------------
__global__ __launch_bounds__(256) void k_pre(
    const float* __restrict__ W, float* __restrict__ WT)
{
    const int d = blockIdx.x * 256 + threadIdx.x;    // 0..2047
    const float4* W4 = reinterpret_cast<const float4*>(W);
    float4 a = W4[d * 2];        // W[d][0..3]
    float4 b = W4[d * 2 + 1];    // W[d][4..7]
    WT[0 * DD + d] = a.x; WT[1 * DD + d] = a.y;
    WT[2 * DD + d] = a.z; WT[3 * DD + d] = a.w;
    WT[4 * DD + d] = b.x; WT[5 * DD + d] = b.y;
    WT[6 * DD + d] = b.z; WT[7 * DD + d] = b.w;
}

// ---------------------------------------------------------------------------
// k_fused: 6144 blocks x 256, role-split.
//   bid <  4096 : logits for token n=bid. Half-wave (32 lanes) per expert;
//                 thread reads 16 float4 of x (same addrs across half-waves
//                 -> broadcast) + 16 float4 of WT (coalesced). f64 acc,
//                 5-level shfl reduce, thread-0 top-2 + softmax.
//   bid >= 4096 : pure streaming zero of a 32 KB dispatcher slice.
// Store-heavy and load-heavy blocks co-resident on each CU: write BW
// overlaps read latency chip-wide instead of inside one thread's vmcnt.
// ---------------------------------------------------------------------------
__global__ __launch_bounds__(256) void k_fused(
    const float* __restrict__ x, const float* __restrict__ WT,
    float* __restrict__ out, int2* __restrict__ choices)
{
    const int tid = threadIdx.x;
    const int bid = blockIdx.x;

    if (bid >= NTOK) {
        // ---- zero role: 32 KB contiguous ---------------------------------
        const int zbid = bid - NTOK;
        float4 z = make_float4(0.f, 0.f, 0.f, 0.f);
        float4* dp = reinterpret_cast<float4*>(out)
                   + (size_t)zbid * (DISP_ELEMS / 4 / ZBLK);   // 2048 f4
        #pragma unroll
        for (int i = 0; i < 8; ++i)
            dp[i * 256 + tid] = z;
        return;
    }

    // ---- logits role ----------------------------------------------------
    const int e   = tid >> 5;         // 0..7, half-wave per expert
    const int seg = tid & 31;         // 0..31
    const int n   = bid;

    const float4* xr = reinterpret_cast<const float4*>(x) + (size_t)n * (DD / 4);
    const float4* wr = reinterpret_cast<const float4*>(WT) + e * (DD / 4);

    double acc = 0.0;
    #pragma unroll
    for (int j = 0; j < 16; ++j) {
        float4 xv = xr[seg + 32 * j];
        float4 wv = wr[seg + 32 * j];
        acc += (double)xv.x * (double)wv.x;
        acc += (double)xv.y * (double)wv.y;
        acc += (double)xv.z * (double)wv.z;
        acc += (double)xv.w * (double)wv.w;
    }

    #pragma unroll
    for (int off = 1; off < 32; off <<= 1)
        acc += __shfl_xor(acc, off, 64);

    __shared__ double red[NE];
    if ((tid & 31) == 0) red[e] = acc;
    __syncthreads();

    if (tid == 0) {
        float lg[NE];
        #pragma unroll
        for (int q = 0; q < NE; ++q) lg[q] = (float)red[q];

        int e0 = 0;
        #pragma unroll
        for (int q = 1; q < NE; ++q) if (lg[q] > lg[e0]) e0 = q;
        int e1 = -1;
        #pragma unroll
        for (int q = 0; q < NE; ++q) {
            if (q == e0) continue;
            if (e1 < 0 || lg[q] > lg[e1]) e1 = q;
        }

        float p1 = __expf(lg[e1] - lg[e0]);    // lg[e0] >= lg[e1]
        float s  = 1.0f + p1;
        out[GATES_OFF + n * 2 + 0] = 1.0f / s;
        out[GATES_OFF + n * 2 + 1] = p1 / s;
        out[IDX_OFF   + n * 2 + 0] = (float)e0;
        out[IDX_OFF   + n * 2 + 1] = (float)e1;
        int2 c; c.x = e0; c.y = e1;
        choices[n] = c;
    }
}

// ---------------------------------------------------------------------------
// k_finish2: 1 block x 1024 (16 waves).
//   Phase A: wave p (pair p = k*8+e) builds per-4-token-group counts from
//            choices and does an exclusive scan over the 1024 groups,
//            leaving bases in LDS histP[group][pair].
//   Phase B: thread g owns group g: rank-in-group + scatter 1.0f into the
//            (already zeroed) dispatcher.
// ---------------------------------------------------------------------------
__global__ __launch_bounds__(1024) void k_finish2(
    const int2* __restrict__ choices, float* __restrict__ out)
{
    __shared__ unsigned histP[NGRP][16];   // 64 KB

    const int lane = threadIdx.x & 63;
    const int p    = threadIdx.x >> 6;     // 0..15
    const int k    = p >> 3, e = p & 7;

    unsigned running = 0;
    #pragma unroll
    for (int chunk = 0; chunk < 16; ++chunk) {
        const int g = chunk * 64 + lane;
        unsigned v = 0;
        #pragma unroll
        for (int t = 0; t < 4; ++t) {
            int2 c = choices[g * 4 + t];
            v += ((k ? c.y : c.x) == e);
        }
        unsigned incl = v;
        #pragma unroll
        for (int off = 1; off < 64; off <<= 1) {
            unsigned u = __shfl_up(incl, off, 64);
            if (lane >= off) incl += u;
        }
        histP[g][p] = incl - v + running;
        running += __shfl(incl, 63, 64);
    }
    __syncthreads();

    // ---- Phase B: scatter ----------------------------------------------
    const int g = threadIdx.x;             // group 0..1023
    int2 c[4];
    #pragma unroll
    for (int t = 0; t < 4; ++t) c[t] = choices[g * 4 + t];

    #pragma unroll
    for (int t = 0; t < 4; ++t) {
        const int n = g * 4 + t;
        const int e0 = c[t].x;
        unsigned r = 0;
        #pragma unroll
        for (int m = 0; m < 4; ++m) if (m < t) r += (c[m].x == e0);
        const unsigned p0 = histP[g][e0] + r;
        if (p0 < CAP) out[((size_t)n * NE + e0) * CAP + p0] = 1.0f;

        const int e1 = c[t].y;
        r = 0;
        #pragma unroll
        for (int m = 0; m < 4; ++m) if (m < t) r += (c[m].y == e1);
        const unsigned p1 = histP[g][8 + e1] + r;
        if (p1 < CAP) out[((size_t)n * NE + e1) * CAP + p1] = 1.0f;
    }
}

extern "C" void kernel_launch(void* const* d_in, const int* in_sizes, int n_in,
                              void* d_out, int out_size, void* d_ws, size_t ws_size,
                              hipStream_t stream) {
    const float* x = (const float*)d_in[0];
    const float* W = (const float*)d_in[1];
    float* out     = (float*)d_out;

    char* ws = (char*)d_ws;
    float* WT     = (float*)ws;                    // 64 KB
    int2*  choices = (int2*)(ws + 65536);          // 32 KB

    hipLaunchKernelGGL(k_pre,     dim3(8),           dim3(256),  0, stream, W, WT);
    hipLaunchKernelGGL(k_fused,   dim3(NTOK + ZBLK), dim3(256),  0, stream,
                       x, WT, out, choices);
    hipLaunchKernelGGL(k_finish2, dim3(1),           dim3(1024), 0, stream,
                       choices, out);
}